// Round 1
// baseline (1058.721 us; speedup 1.0000x reference)
//
#include <hip/hip_runtime.h>
#include <stdint.h>

#define EPS 1e-5f

typedef __attribute__((ext_vector_type(8))) __bf16 bf16x8;
typedef __attribute__((ext_vector_type(4))) float f32x4;

__device__ __forceinline__ int swz4(int r) { return (r ^ (r >> 2)) & 3; }

__device__ __forceinline__ unsigned short f2bf(float f) {
  union { float f; unsigned u; } v; v.f = f;
  unsigned r = v.u + 0x7fffu + ((v.u >> 16) & 1u);
  return (unsigned short)(r >> 16);
}

__device__ __forceinline__ void glds16(const unsigned short* g, unsigned short* l) {
  __builtin_amdgcn_global_load_lds(
      (const __attribute__((address_space(1))) void*)g,
      (__attribute__((address_space(3))) void*)l, 16, 0, 0);
}

// ---------------------------------------------------------------------------
// Pack W [c2][c1][13][13] f32 -> bf16 per-K-step tiles that are the exact
// linear LDS image of the A tile (swizzle baked in).
// K order: k = ((kh*8 + c1c)*13 + kw)*32 + c1i   (c1 = c1c*32 + c1i)
// Tile (c2t, ks): [m 128][slot 4][j 8], slot = (c1i>>3) ^ swz4(m), j = c1i&7
// ---------------------------------------------------------------------------
__global__ __launch_bounds__(256) void pack_w_kernel(
    const float* __restrict__ W, unsigned short* __restrict__ Wp) {
  const int blk = blockIdx.x;               // c2*13 + kh
  const int c2 = blk / 13, kh = blk - c2 * 13;
  const int c1 = threadIdx.x;
  const int c2t = c2 >> 7, m = c2 & 127;
  const int c1c = c1 >> 5, c1i = c1 & 31;
  const float* src = W + (((size_t)(c2 * 256 + c1)) * 13 + kh) * 13;
  const int rowoff = (((c1i >> 3) ^ swz4(m)) << 3) + (c1i & 7);
#pragma unroll
  for (int kw = 0; kw < 13; ++kw) {
    const int ks = (kh * 8 + c1c) * 13 + kw;
    const size_t dst = (((size_t)c2t * 1352 + ks) * 128 + m) * 32 + rowoff;
    Wp[dst] = f2bf(src[kw]);
  }
}

// ---------------------------------------------------------------------------
// Implicit-GEMM conv + BN + SiLU.
// Block: 256 thr (4 waves, 2x2), tile = 128 c2 x 128 spatial (2 rows x 64 w).
// Grid: 512 = 2 c2-tiles x (8 b x 32 row-pairs).
// ---------------------------------------------------------------------------
__global__ __launch_bounds__(256, 2) void conv_bn_silu_kernel(
    const unsigned short* __restrict__ Wp, const float* __restrict__ x,
    const float* __restrict__ gamma, const float* __restrict__ beta,
    const float* __restrict__ mean, const float* __restrict__ var,
    float* __restrict__ out) {
  __shared__ __align__(16) unsigned short Alds[128 * 32];    // 8 KiB
  __shared__ __align__(16) unsigned short Wnd[2 * 76 * 32];  // 9.5 KiB window
  __shared__ float s_scale[128], s_shift[128];

  const int tid = threadIdx.x;
  const int bid = blockIdx.x;
  const int c2t = bid >> 8;
  const int sp = bid & 255;
  const int b = sp >> 5;
  const int h0 = (sp & 31) * 2;

  const int wid = tid >> 6, lane = tid & 63;
  const int wr = wid >> 1, wc = wid & 1;
  const int hi = lane >> 4, lo = lane & 15;

  if (tid < 128) {
    const int c2 = c2t * 128 + tid;
    const float inv = gamma[c2] * rsqrtf(var[c2] + EPS);
    s_scale[tid] = inv;
    s_shift[tid] = beta[c2] - mean[c2] * inv;
  }

  // constant per-thread fragment offsets
  int aoff[4];
#pragma unroll
  for (int mf = 0; mf < 4; ++mf) {
    const int m = wr * 64 + mf * 16 + lo;
    aoff[mf] = m * 64 + ((hi ^ swz4(m)) << 4);   // byte offset into Alds
  }
  int ndh[4], nw[4];
#pragma unroll
  for (int nf = 0; nf < 4; ++nf) {
    const int n = wc * 64 + nf * 16 + lo;
    ndh[nf] = n >> 6;
    nw[nf] = n & 63;
  }

  // window-staging decomposition: tid = c1i*8 + dh*4 + q
  const int s_c1i = tid >> 3;
  const int s_dh = (tid >> 2) & 1;
  const int s_q = tid & 3;

  f32x4 acc[4][4];
  const f32x4 zero4 = {0.f, 0.f, 0.f, 0.f};
#pragma unroll
  for (int i = 0; i < 4; ++i)
#pragma unroll
    for (int j = 0; j < 4; ++j) acc[i][j] = zero4;

  const char* abase = (const char*)Alds;
  const char* wbase = (const char*)Wnd;

  for (int kh = 0; kh < 13; ++kh) {
    for (int c1c = 0; c1c < 8; ++c1c) {
      __syncthreads();  // protect Wnd + Alds from previous iteration's reads
      // ---- stage sliding window: x[b][c1c*32+c1i][h0+dh+kh-6][-6..69]
      {
        const int c1 = c1c * 32 + s_c1i;
        const int row = h0 + s_dh + kh - 6;
        const bool rok = (unsigned)row < 64u;
        const float* xrow = x + (((size_t)(b * 256 + c1) * 64 + row) * 64);
#pragma unroll
        for (int i = 0; i < 19; ++i) {
          const int col = s_q * 19 + i;  // 0..75
          const int ic = col - 6;
          const float v = (rok && (unsigned)ic < 64u) ? xrow[ic] : 0.f;
          const int addr = (s_dh * 76 + col) * 32 +
                           (((s_c1i >> 3) ^ swz4(col)) << 3) + (s_c1i & 7);
          Wnd[addr] = f2bf(v);
        }
      }
      const int ks0 = (kh * 8 + c1c) * 13;
      for (int kw = 0; kw < 13; ++kw) {
        if (kw) __syncthreads();  // protect Alds from previous step's reads
        // ---- stage A tile (8 KiB) async global->LDS, linear copy
        {
          const unsigned short* wt = Wp + (((size_t)c2t * 1352 + ks0 + kw) << 12);
          const int off0 = wid * 1024 + lane * 8;  // ushort elems
          glds16(wt + off0, Alds + wid * 1024);
          glds16(wt + off0 + 512, Alds + wid * 1024 + 512);
        }
        __syncthreads();  // drain vmcnt(glds) + lgkm(window writes)
        // ---- fragments + 16 MFMA
        bf16x8 afr[4], bfr[4];
#pragma unroll
        for (int mf = 0; mf < 4; ++mf)
          afr[mf] = *(const bf16x8*)(abase + aoff[mf]);
#pragma unroll
        for (int nf = 0; nf < 4; ++nf) {
          const int col = nw[nf] + kw;
          bfr[nf] = *(const bf16x8*)(wbase + (ndh[nf] * 76 + col) * 64 +
                                     ((hi ^ swz4(col)) << 4));
        }
#pragma unroll
        for (int mf = 0; mf < 4; ++mf)
#pragma unroll
          for (int nf = 0; nf < 4; ++nf)
            acc[mf][nf] = __builtin_amdgcn_mfma_f32_16x16x32_bf16(
                afr[mf], bfr[nf], acc[mf][nf], 0, 0, 0);
      }
    }
  }

  // ---- epilogue: BN + SiLU, f32 stores
  // C/D layout (verified m89): col = lane&15, row = (lane>>4)*4 + reg
#pragma unroll
  for (int mf = 0; mf < 4; ++mf) {
#pragma unroll
    for (int r = 0; r < 4; ++r) {
      const int c2l = wr * 64 + mf * 16 + hi * 4 + r;
      const float inv = s_scale[c2l];
      const float bia = s_shift[c2l];
      const size_t obase = ((size_t)(b * 256 + c2t * 128 + c2l)) * 4096;
#pragma unroll
      for (int nf = 0; nf < 4; ++nf) {
        const int n = wc * 64 + nf * 16 + lo;
        const float y = acc[mf][nf][r] * inv + bia;
        out[obase + (size_t)(h0 + (n >> 6)) * 64 + (n & 63)] =
            y / (1.f + __expf(-y));
      }
    }
  }
}

// ---------------------------------------------------------------------------
// Safety-net fallback if workspace is too small for the packed weights.
// ---------------------------------------------------------------------------
__global__ void naive_conv_kernel(
    const float* __restrict__ x, const float* __restrict__ W,
    const float* __restrict__ gamma, const float* __restrict__ beta,
    const float* __restrict__ mean, const float* __restrict__ var,
    float* __restrict__ out) {
  const int idx = blockIdx.x * 256 + threadIdx.x;
  if (idx >= 8 * 256 * 64 * 64) return;
  const int w = idx & 63, h = (idx >> 6) & 63;
  const int c2 = (idx >> 12) & 255, b = idx >> 20;
  float s = 0.f;
  for (int c1 = 0; c1 < 256; ++c1) {
    const float* xp = x + ((size_t)(b * 256 + c1) * 4096);
    const float* wp = W + ((size_t)(c2 * 256 + c1) * 169);
    for (int kh = 0; kh < 13; ++kh) {
      const int r = h + kh - 6;
      if ((unsigned)r >= 64u) continue;
      for (int kw = 0; kw < 13; ++kw) {
        const int c = w + kw - 6;
        if ((unsigned)c >= 64u) continue;
        s += xp[r * 64 + c] * wp[kh * 13 + kw];
      }
    }
  }
  const float inv = gamma[c2] * rsqrtf(var[c2] + EPS);
  const float y = s * inv + (beta[c2] - mean[c2] * inv);
  out[idx] = y / (1.f + __expf(-y));
}

extern "C" void kernel_launch(void* const* d_in, const int* in_sizes, int n_in,
                              void* d_out, int out_size, void* d_ws, size_t ws_size,
                              hipStream_t stream) {
  const float* x = (const float*)d_in[0];
  const float* W = (const float*)d_in[1];
  const float* gamma = (const float*)d_in[2];
  const float* beta = (const float*)d_in[3];
  const float* mean = (const float*)d_in[4];
  const float* var = (const float*)d_in[5];
  float* out = (float*)d_out;

  const size_t need = (size_t)256 * 43264 * sizeof(unsigned short);  // 22.2 MB
  if (ws_size >= need) {
    unsigned short* Wp = (unsigned short*)d_ws;
    pack_w_kernel<<<256 * 13, 256, 0, stream>>>(W, Wp);
    conv_bn_silu_kernel<<<512, 256, 0, stream>>>(Wp, x, gamma, beta, mean, var, out);
  } else {
    naive_conv_kernel<<<(8 * 256 * 64 * 64 + 255) / 256, 256, 0, stream>>>(
        x, W, gamma, beta, mean, var, out);
  }
}

// Round 2
// 719.956 us; speedup vs baseline: 1.4705x; 1.4705x over previous
//
#include <hip/hip_runtime.h>
#include <stdint.h>

#define EPS 1e-5f

typedef __attribute__((ext_vector_type(8))) __bf16 bf16x8;
typedef __attribute__((ext_vector_type(4))) float f32x4;

__device__ __forceinline__ int swz4(int r) { return (r ^ (r >> 2)) & 3; }

__device__ __forceinline__ unsigned short f2bf(float f) {
  union { float f; unsigned u; } v; v.f = f;
  unsigned r = v.u + 0x7fffu + ((v.u >> 16) & 1u);
  return (unsigned short)(r >> 16);
}

__device__ __forceinline__ void glds16(const unsigned short* g, unsigned short* l) {
  __builtin_amdgcn_global_load_lds(
      (const __attribute__((address_space(1))) void*)g,
      (__attribute__((address_space(3))) void*)l, 16, 0, 0);
}

template <int N>
__device__ __forceinline__ void vmwait() {
  asm volatile("s_waitcnt vmcnt(%0)" ::"n"(N) : "memory");
}

// ---------------------------------------------------------------------------
// Pack W [c2][c1][13][13] f32 -> bf16 per-K-step tiles = exact linear LDS
// image of the A tile (chunk swizzle baked in).
// K order: k = ((kh*8 + c1c)*13 + kw)*32 + c1i
// ---------------------------------------------------------------------------
__global__ __launch_bounds__(256) void pack_w_kernel(
    const float* __restrict__ W, unsigned short* __restrict__ Wp) {
  const int blk = blockIdx.x;  // c2*13 + kh
  const int c2 = blk / 13, kh = blk - c2 * 13;
  const int c1 = threadIdx.x;
  const int c2t = c2 >> 7, m = c2 & 127;
  const int c1c = c1 >> 5, c1i = c1 & 31;
  const float* src = W + (((size_t)(c2 * 256 + c1)) * 13 + kh) * 13;
  const int rowoff = (((c1i >> 3) ^ swz4(m)) << 3) + (c1i & 7);
#pragma unroll
  for (int kw = 0; kw < 13; ++kw) {
    const int ks = (kh * 8 + c1c) * 13 + kw;
    const size_t dst = (((size_t)c2t * 1352 + ks) * 128 + m) * 32 + rowoff;
    Wp[dst] = f2bf(src[kw]);
  }
}

// ---------------------------------------------------------------------------
// Pack x [b][c1][64][64] f32 -> xT[b][c1c][rowp 76][colp 80][c1i 32] bf16,
// zero-padded halo (rowp = row+6, colp = ic+8), chunk swizzle baked in:
// 16B chunk u of (rowp,colp) is stored at slot u ^ swz4(colp).
// ---------------------------------------------------------------------------
__global__ __launch_bounds__(256) void pack_xt_kernel(
    const float* __restrict__ x, unsigned short* __restrict__ xT) {
  const int blk = blockIdx.x;  // (b*8 + c1c)*76 + rowp ; 4864 blocks
  const int rowp = blk % 76;
  const int bc = blk / 76;
  const int c1c = bc & 7, b = bc >> 3;
  const int row = rowp - 6;
  const bool rok = (unsigned)row < 64u;
  unsigned short* dst = xT + (size_t)blk * 2560;
  const float* srcb = x + (size_t)(b * 256 + c1c * 32) * 4096 +
                      (rok ? row * 64 : 0);
#pragma unroll
  for (int e = 0; e < 10; ++e) {
    const int idx = e * 256 + threadIdx.x;  // 0..2559
    const int colp = idx >> 5, c1i = idx & 31;
    const int ic = colp - 8;
    const float v = (rok && (unsigned)ic < 64u) ? srcb[(size_t)c1i * 4096 + ic] : 0.f;
    dst[colp * 32 + ((((c1i >> 3) ^ swz4(colp)) << 3)) + (c1i & 7)] = f2bf(v);
  }
}

// ---------------------------------------------------------------------------
// Implicit-GEMM conv + BN + SiLU, double-buffered glds pipeline with counted
// vmcnt (T3+T4). Block: 256 thr (4 waves 2x2), tile 128 c2 x 128 spatial.
// ---------------------------------------------------------------------------
__global__ __launch_bounds__(256, 2) void conv2_kernel(
    const unsigned short* __restrict__ Wp, const unsigned short* __restrict__ xT,
    const float* __restrict__ gamma, const float* __restrict__ beta,
    const float* __restrict__ mean, const float* __restrict__ var,
    float* __restrict__ out) {
  __shared__ __align__(16) unsigned short Albuf[2][4096];  // 2 x 8 KiB
  __shared__ __align__(16) unsigned short Wbuf[2][6144];   // 2 x 12 KiB
  __shared__ float s_scale[128], s_shift[128];

  const int tid = threadIdx.x;
  const int bid = blockIdx.x;
  const int b = bid & 7;  // XCD-aware: all blocks on XCD k share batch image k
  const int rest = bid >> 3;
  const int hpair = rest & 31;
  const int c2t = rest >> 5;
  const int h0 = hpair * 2;

  const int wid = tid >> 6, lane = tid & 63;
  const int wr = wid >> 1, wc = wid & 1;
  const int hi = lane >> 4, lo = lane & 15;

  if (tid < 128) {
    const int c2 = c2t * 128 + tid;
    const float inv = gamma[c2] * rsqrtf(var[c2] + EPS);
    s_scale[tid] = inv;
    s_shift[tid] = beta[c2] - mean[c2] * inv;
  }

  int aoff[4];
#pragma unroll
  for (int mf = 0; mf < 4; ++mf) {
    const int m = wr * 64 + mf * 16 + lo;
    aoff[mf] = m * 64 + ((hi ^ swz4(m)) << 4);  // byte offset in A tile
  }
  int ndh[4], nw[4];
#pragma unroll
  for (int nf = 0; nf < 4; ++nf) {
    const int n = wc * 64 + nf * 16 + lo;
    ndh[nf] = n >> 6;
    nw[nf] = n & 63;
  }

  const int aSrcOff = wid * 1024 + lane * 8;  // ushort units
  const int aDstOff = wid * 1024;
  const int wSrcOff = wid * 1536 + lane * 8;
  const int wDstOff = wid * 1536;

  const size_t c2base = (size_t)c2t * 1352;
  const int bc8 = b * 8;

  auto wtile = [&](int T) -> const unsigned short* {
    const int kh = T >> 3, c1c = T & 7;
    return xT + (size_t)((bc8 + c1c) * 76 + h0 + kh) * 2560;
  };

  f32x4 acc[4][4];
  const f32x4 zero4 = {0.f, 0.f, 0.f, 0.f};
#pragma unroll
  for (int i = 0; i < 4; ++i)
#pragma unroll
    for (int j = 0; j < 4; ++j) acc[i][j] = zero4;

  // ---- prologue: A(0) -> Albuf[0], window(T=0) -> Wbuf[0]
  {
    const unsigned short* at = Wp + (c2base << 12);
    glds16(at + aSrcOff, &Albuf[0][aDstOff]);
    glds16(at + aSrcOff + 512, &Albuf[0][aDstOff + 512]);
    const unsigned short* ws = wtile(0);
    glds16(ws + wSrcOff, &Wbuf[0][wDstOff]);
    glds16(ws + wSrcOff + 512, &Wbuf[0][wDstOff + 512]);
    glds16(ws + wSrcOff + 1024, &Wbuf[0][wDstOff + 1024]);
  }

// one K-step: prefetch A(s+1) (+ window round on kw 9..11), counted vmcnt,
// raw barriers, 8 ds_read_b128 + 16 MFMA, lgkm drain, barrier.
#define STEP(KW, CAP, CWP, TT, WSN)                                          \
  {                                                                           \
    {                                                                         \
      int sn = (TT) * 13 + (KW) + 1;                                          \
      if (sn == 1352) sn = 0;                                                 \
      const unsigned short* at = Wp + ((c2base + (size_t)sn) << 12);          \
      glds16(at + aSrcOff, &Albuf[(CAP) ^ 1][aDstOff]);                       \
      glds16(at + aSrcOff + 512, &Albuf[(CAP) ^ 1][aDstOff + 512]);           \
    }                                                                         \
    if ((KW) >= 9 && (KW) <= 11) {                                            \
      glds16((WSN) + wSrcOff + ((KW) - 9) * 512,                              \
             &Wbuf[(CWP) ^ 1][wDstOff + ((KW) - 9) * 512]);                   \
    }                                                                         \
    vmwait<(((KW) == 9 || (KW) == 12)                                         \
                ? 3                                                           \
                : (((KW) == 10 || (KW) == 11) ? 4 : 2))>();                   \
    __builtin_amdgcn_s_barrier();                                             \
    asm volatile("" ::: "memory");                                            \
    {                                                                         \
      const char* ab = (const char*)&Albuf[(CAP)][0];                         \
      const char* wb = (const char*)&Wbuf[(CWP)][0];                          \
      bf16x8 afr[4], bfr[4];                                                  \
      _Pragma("unroll") for (int mf = 0; mf < 4; ++mf)                        \
          afr[mf] = *(const bf16x8*)(ab + aoff[mf]);                          \
      _Pragma("unroll") for (int nf = 0; nf < 4; ++nf) {                      \
        const int wcol = nw[nf] + (KW) + 2;                                   \
        bfr[nf] = *(const bf16x8*)(wb + (ndh[nf] * 80 + wcol) * 64 +          \
                                   ((hi ^ swz4(wcol)) << 4));                 \
      }                                                                       \
      _Pragma("unroll") for (int mf = 0; mf < 4; ++mf)                        \
          _Pragma("unroll") for (int nf = 0; nf < 4; ++nf)                    \
              acc[mf][nf] = __builtin_amdgcn_mfma_f32_16x16x32_bf16(          \
                  afr[mf], bfr[nf], acc[mf][nf], 0, 0, 0);                    \
    }                                                                         \
    asm volatile("s_waitcnt lgkmcnt(0)" ::: "memory");                        \
    __builtin_amdgcn_s_barrier();                                             \
  }

  for (int u = 0; u < 52; ++u) {
    const int T0 = u * 2, T1 = T0 + 1;
    const unsigned short* wsN1 = wtile(T1);
    const unsigned short* wsN2 = wtile((T1 + 1 == 104) ? 0 : T1 + 1);
    STEP(0, 0, 0, T0, wsN1)
    STEP(1, 1, 0, T0, wsN1)
    STEP(2, 0, 0, T0, wsN1)
    STEP(3, 1, 0, T0, wsN1)
    STEP(4, 0, 0, T0, wsN1)
    STEP(5, 1, 0, T0, wsN1)
    STEP(6, 0, 0, T0, wsN1)
    STEP(7, 1, 0, T0, wsN1)
    STEP(8, 0, 0, T0, wsN1)
    STEP(9, 1, 0, T0, wsN1)
    STEP(10, 0, 0, T0, wsN1)
    STEP(11, 1, 0, T0, wsN1)
    STEP(12, 0, 0, T0, wsN1)
    STEP(0, 1, 1, T1, wsN2)
    STEP(1, 0, 1, T1, wsN2)
    STEP(2, 1, 1, T1, wsN2)
    STEP(3, 0, 1, T1, wsN2)
    STEP(4, 1, 1, T1, wsN2)
    STEP(5, 0, 1, T1, wsN2)
    STEP(6, 1, 1, T1, wsN2)
    STEP(7, 0, 1, T1, wsN2)
    STEP(8, 1, 1, T1, wsN2)
    STEP(9, 0, 1, T1, wsN2)
    STEP(10, 1, 1, T1, wsN2)
    STEP(11, 0, 1, T1, wsN2)
    STEP(12, 1, 1, T1, wsN2)
  }
#undef STEP

  // ---- epilogue: BN + SiLU. C/D layout: col = lane&15, row = (lane>>4)*4+reg
#pragma unroll
  for (int mf = 0; mf < 4; ++mf) {
#pragma unroll
    for (int r = 0; r < 4; ++r) {
      const int c2l = wr * 64 + mf * 16 + hi * 4 + r;
      const float inv = s_scale[c2l];
      const float bia = s_shift[c2l];
      const size_t obase = ((size_t)(b * 256 + c2t * 128 + c2l)) * 4096;
#pragma unroll
      for (int nf = 0; nf < 4; ++nf) {
        const int n = wc * 64 + nf * 16 + lo;
        const float y = acc[mf][nf][r] * inv + bia;
        out[obase + (size_t)(h0 + (n >> 6)) * 64 + (n & 63)] =
            y / (1.f + __expf(-y));
      }
    }
  }
}

// ---------------------------------------------------------------------------
// Round-1 kernel kept as fallback when ws can hold Wp but not xT.
// ---------------------------------------------------------------------------
__global__ __launch_bounds__(256, 2) void conv_bn_silu_kernel(
    const unsigned short* __restrict__ Wp, const float* __restrict__ x,
    const float* __restrict__ gamma, const float* __restrict__ beta,
    const float* __restrict__ mean, const float* __restrict__ var,
    float* __restrict__ out) {
  __shared__ __align__(16) unsigned short Alds[128 * 32];
  __shared__ __align__(16) unsigned short Wnd[2 * 76 * 32];
  __shared__ float s_scale[128], s_shift[128];

  const int tid = threadIdx.x;
  const int bid = blockIdx.x;
  const int c2t = bid >> 8;
  const int sp = bid & 255;
  const int b = sp >> 5;
  const int h0 = (sp & 31) * 2;

  const int wid = tid >> 6, lane = tid & 63;
  const int wr = wid >> 1, wc = wid & 1;
  const int hi = lane >> 4, lo = lane & 15;

  if (tid < 128) {
    const int c2 = c2t * 128 + tid;
    const float inv = gamma[c2] * rsqrtf(var[c2] + EPS);
    s_scale[tid] = inv;
    s_shift[tid] = beta[c2] - mean[c2] * inv;
  }

  int aoff[4];
#pragma unroll
  for (int mf = 0; mf < 4; ++mf) {
    const int m = wr * 64 + mf * 16 + lo;
    aoff[mf] = m * 64 + ((hi ^ swz4(m)) << 4);
  }
  int ndh[4], nw[4];
#pragma unroll
  for (int nf = 0; nf < 4; ++nf) {
    const int n = wc * 64 + nf * 16 + lo;
    ndh[nf] = n >> 6;
    nw[nf] = n & 63;
  }

  const int s_c1i = tid >> 3;
  const int s_dh = (tid >> 2) & 1;
  const int s_q = tid & 3;

  f32x4 acc[4][4];
  const f32x4 zero4 = {0.f, 0.f, 0.f, 0.f};
#pragma unroll
  for (int i = 0; i < 4; ++i)
#pragma unroll
    for (int j = 0; j < 4; ++j) acc[i][j] = zero4;

  const char* abase = (const char*)Alds;
  const char* wbase = (const char*)Wnd;

  for (int kh = 0; kh < 13; ++kh) {
    for (int c1c = 0; c1c < 8; ++c1c) {
      __syncthreads();
      {
        const int c1 = c1c * 32 + s_c1i;
        const int row = h0 + s_dh + kh - 6;
        const bool rok = (unsigned)row < 64u;
        const float* xrow = x + (((size_t)(b * 256 + c1) * 64 + row) * 64);
#pragma unroll
        for (int i = 0; i < 19; ++i) {
          const int col = s_q * 19 + i;
          const int ic = col - 6;
          const float v = (rok && (unsigned)ic < 64u) ? xrow[ic] : 0.f;
          const int addr = (s_dh * 76 + col) * 32 +
                           (((s_c1i >> 3) ^ swz4(col)) << 3) + (s_c1i & 7);
          Wnd[addr] = f2bf(v);
        }
      }
      const int ks0 = (kh * 8 + c1c) * 13;
      for (int kw = 0; kw < 13; ++kw) {
        if (kw) __syncthreads();
        {
          const unsigned short* wt = Wp + (((size_t)c2t * 1352 + ks0 + kw) << 12);
          const int off0 = wid * 1024 + lane * 8;
          glds16(wt + off0, Alds + wid * 1024);
          glds16(wt + off0 + 512, Alds + wid * 1024 + 512);
        }
        __syncthreads();
        bf16x8 afr[4], bfr[4];
#pragma unroll
        for (int mf = 0; mf < 4; ++mf)
          afr[mf] = *(const bf16x8*)(abase + aoff[mf]);
#pragma unroll
        for (int nf = 0; nf < 4; ++nf) {
          const int col = nw[nf] + kw;
          bfr[nf] = *(const bf16x8*)(wbase + (ndh[nf] * 76 + col) * 64 +
                                     ((hi ^ swz4(col)) << 4));
        }
#pragma unroll
        for (int mf = 0; mf < 4; ++mf)
#pragma unroll
          for (int nf = 0; nf < 4; ++nf)
            acc[mf][nf] = __builtin_amdgcn_mfma_f32_16x16x32_bf16(
                afr[mf], bfr[nf], acc[mf][nf], 0, 0, 0);
      }
    }
  }

#pragma unroll
  for (int mf = 0; mf < 4; ++mf) {
#pragma unroll
    for (int r = 0; r < 4; ++r) {
      const int c2l = wr * 64 + mf * 16 + hi * 4 + r;
      const float inv = s_scale[c2l];
      const float bia = s_shift[c2l];
      const size_t obase = ((size_t)(b * 256 + c2t * 128 + c2l)) * 4096;
#pragma unroll
      for (int nf = 0; nf < 4; ++nf) {
        const int n = wc * 64 + nf * 16 + lo;
        const float y = acc[mf][nf][r] * inv + bia;
        out[obase + (size_t)(h0 + (n >> 6)) * 64 + (n & 63)] =
            y / (1.f + __expf(-y));
      }
    }
  }
}

__global__ void naive_conv_kernel(
    const float* __restrict__ x, const float* __restrict__ W,
    const float* __restrict__ gamma, const float* __restrict__ beta,
    const float* __restrict__ mean, const float* __restrict__ var,
    float* __restrict__ out) {
  const int idx = blockIdx.x * 256 + threadIdx.x;
  if (idx >= 8 * 256 * 64 * 64) return;
  const int w = idx & 63, h = (idx >> 6) & 63;
  const int c2 = (idx >> 12) & 255, b = idx >> 20;
  float s = 0.f;
  for (int c1 = 0; c1 < 256; ++c1) {
    const float* xp = x + ((size_t)(b * 256 + c1) * 4096);
    const float* wp = W + ((size_t)(c2 * 256 + c1) * 169);
    for (int kh = 0; kh < 13; ++kh) {
      const int r = h + kh - 6;
      if ((unsigned)r >= 64u) continue;
      for (int kw = 0; kw < 13; ++kw) {
        const int c = w + kw - 6;
        if ((unsigned)c >= 64u) continue;
        s += xp[r * 64 + c] * wp[kh * 13 + kw];
      }
    }
  }
  const float inv = gamma[c2] * rsqrtf(var[c2] + EPS);
  const float y = s * inv + (beta[c2] - mean[c2] * inv);
  out[idx] = y / (1.f + __expf(-y));
}

extern "C" void kernel_launch(void* const* d_in, const int* in_sizes, int n_in,
                              void* d_out, int out_size, void* d_ws, size_t ws_size,
                              hipStream_t stream) {
  const float* x = (const float*)d_in[0];
  const float* W = (const float*)d_in[1];
  const float* gamma = (const float*)d_in[2];
  const float* beta = (const float*)d_in[3];
  const float* mean = (const float*)d_in[4];
  const float* var = (const float*)d_in[5];
  float* out = (float*)d_out;

  const size_t WP_BYTES = (size_t)256 * 43264 * 2;       // 22,151,168
  const size_t XT_BYTES = (size_t)12455424 * 2;          // 24,910,848 (incl pad)

  if (ws_size >= WP_BYTES + XT_BYTES) {
    unsigned short* Wp = (unsigned short*)d_ws;
    unsigned short* xT = (unsigned short*)((char*)d_ws + WP_BYTES);
    pack_w_kernel<<<256 * 13, 256, 0, stream>>>(W, Wp);
    pack_xt_kernel<<<8 * 8 * 76, 256, 0, stream>>>(x, xT);
    conv2_kernel<<<512, 256, 0, stream>>>(Wp, xT, gamma, beta, mean, var, out);
  } else if (ws_size >= WP_BYTES) {
    unsigned short* Wp = (unsigned short*)d_ws;
    pack_w_kernel<<<256 * 13, 256, 0, stream>>>(W, Wp);
    conv_bn_silu_kernel<<<512, 256, 0, stream>>>(Wp, x, gamma, beta, mean, var, out);
  } else {
    naive_conv_kernel<<<(8 * 256 * 64 * 64 + 255) / 256, 256, 0, stream>>>(
        x, W, gamma, beta, mean, var, out);
  }
}